// Round 6
// baseline (1888.036 us; speedup 1.0000x reference)
//
#include <hip/hip_runtime.h>
#include <cstdint>
#include <cstddef>

// Problem constants
#define NUM_C 4096
#define BB 32
#define TT 512
#define DD 128
#define MM 50

using ull = unsigned long long;

__device__ __forceinline__ float sigmoidf_(float x){ return 1.0f/(1.0f + expf(-x)); }

// Quad reduction via DPP (VALU pipe) — PROVEN in round-4 kernel.
// quad_perm xor1 = [1,0,3,2] -> 0xB1 ; xor2 = [2,3,0,1] -> 0x4E
__device__ __forceinline__ float quadSum_(float v){
  int t = __builtin_amdgcn_update_dpp(0, __float_as_int(v), 0xB1, 0xF, 0xF, true);
  v += __int_as_float(t);
  t = __builtin_amdgcn_update_dpp(0, __float_as_int(v), 0x4E, 0xF, 0xF, true);
  v += __int_as_float(t);
  return v;
}

// 8-lane butterfly via shfl_xor (proven primitive, all 8 lanes get the total)
__device__ __forceinline__ float sum8_(float v){
  v += __shfl_xor(v, 1);
  v += __shfl_xor(v, 2);
  v += __shfl_xor(v, 4);
  return v;
}

__device__ __forceinline__ float dot16_(const float4 xa, const float4 xb,
                                        const float4 xc, const float4 xd,
                                        const float* w){
  float s0 = xa.x*w[0]  + xa.y*w[1]  + xa.z*w[2]  + xa.w*w[3];
  float s1 = xb.x*w[4]  + xb.y*w[5]  + xb.z*w[6]  + xb.w*w[7];
  float s2 = xc.x*w[8]  + xc.y*w[9]  + xc.z*w[10] + xc.w*w[11];
  float s3 = xd.x*w[12] + xd.y*w[13] + xd.z*w[14] + xd.w*w[15];
  return (s0+s1)+(s2+s3);
}

// ---------------------------------------------------------------------------
// Kernel A: parallel precompute (unchanged, proven).
// ---------------------------------------------------------------------------
__global__ __launch_bounds__(256) void kPre(
    const int* __restrict__ q, const int* __restrict__ r,
    const float* __restrict__ k_emb, const float* __restrict__ Mk,
    const float* __restrict__ f_W, const float* __restrict__ f_b,
    const float* __restrict__ a_W, const float* __restrict__ a_b,
    float* __restrict__ wAll, ull* __restrict__ keyLo, ull* __restrict__ keyHi,
    float* __restrict__ fpre, float* __restrict__ ypre)
{
  const int b = blockIdx.y, t0 = blockIdx.x * 32, tid = threadIdx.x;
  __shared__ __align__(16) float sK[32*129];
  __shared__ int sQ[32];
  __shared__ int sR[32];
  __shared__ union UU {
    struct { float sMk[MM*129]; double sZ[32*MM]; } p2;
    float sW2[128*65];
  } u;

  if (tid < 32){ sQ[tid] = q[b*TT + t0 + tid]; sR[tid] = r[b*TT + t0 + tid]; }
  __syncthreads();
  for (int i = tid; i < 32*128; i += 256){
    int tl = i >> 7, j = i & 127;
    sK[tl*129 + j] = k_emb[(size_t)sQ[tl]*DD + j];
  }
  for (int i = tid; i < MM*128; i += 256){
    int m = i >> 7, j = i & 127;
    u.p2.sMk[m*129 + j] = Mk[i];
  }
  __syncthreads();

  for (int idx = tid; idx < 32*MM; idx += 256){
    int tl = idx / MM, m = idx - tl*MM;
    double z = 0.0;
    for (int j = 0; j < DD; j++)
      z += (double)sK[tl*129 + j] * (double)u.p2.sMk[m*129 + j];
    u.p2.sZ[tl*MM + m] = z;
  }
  __syncthreads();

  {
    int tl = tid >> 3, l8 = tid & 7;
    double zmax = -1e300;
    for (int m = l8; m < MM; m += 8) zmax = fmax(zmax, u.p2.sZ[tl*MM + m]);
    for (int s = 1; s < 8; s <<= 1) zmax = fmax(zmax, __shfl_xor(zmax, s));
    double se = 0.0;
    for (int m = l8; m < MM; m += 8){
      double e = exp(u.p2.sZ[tl*MM + m] - zmax);
      u.p2.sZ[tl*MM + m] = e;
      se += e;
    }
    for (int s = 1; s < 8; s <<= 1) se += __shfl_xor(se, s);
    double inv = 1.0 / se;
    ull klo = 0, khi = 0;
    for (int m = l8; m < MM; m += 8){
      double w = u.p2.sZ[tl*MM + m] * inv;
      wAll[((size_t)(b*TT + t0 + tl))*MM + m] = (float)w;
      double tw = fmin((w - 0.075)/(0.088 - 0.075), (1.0 - w)/(1.0 - 0.088));
      tw = fmax(tw, 0.0);
      ull iv = (tw >= 0.6) ? 2ull : ((tw >= 0.1) ? 1ull : 0ull);
      if (m < 32) klo |= iv << (2*m); else khi |= iv << (2*(m-32));
    }
    for (int s = 1; s < 8; s <<= 1){ klo |= __shfl_xor(klo, s); khi |= __shfl_xor(khi, s); }
    if (l8 == 0){ keyLo[b*TT + t0 + tl] = klo; keyHi[b*TT + t0 + tl] = khi; }
  }

  {
    const int dq = tid & 31, tq = tid >> 5;
    float acc[4][4];
    #pragma unroll
    for (int a = 0; a < 4; a++){ acc[a][0]=0.f; acc[a][1]=0.f; acc[a][2]=0.f; acc[a][3]=0.f; }
    for (int jh = 0; jh < 2; jh++){
      __syncthreads();
      for (int i = tid; i < 128*64; i += 256){
        int dd = i >> 6, jj = i & 63;
        u.sW2[dd*65 + jj] = f_W[dd*256 + 128 + jh*64 + jj];
      }
      __syncthreads();
      for (int jj = 0; jj < 64; jj++){
        float kv[4], wv[4];
        #pragma unroll
        for (int a = 0; a < 4; a++) kv[a] = sK[(tq*4 + a)*129 + jh*64 + jj];
        #pragma unroll
        for (int c = 0; c < 4; c++) wv[c] = u.sW2[(dq*4 + c)*65 + jj];
        #pragma unroll
        for (int a = 0; a < 4; a++){
          acc[a][0] += kv[a]*wv[0]; acc[a][1] += kv[a]*wv[1];
          acc[a][2] += kv[a]*wv[2]; acc[a][3] += kv[a]*wv[3];
        }
      }
    }
    #pragma unroll
    for (int a = 0; a < 4; a++){
      int tl = tq*4 + a;
      #pragma unroll
      for (int c = 0; c < 4; c++){
        int d = dq*4 + c;
        fpre[((size_t)(b*TT + t0 + tl))*DD + d] = acc[a][c] + f_b[d];
      }
    }
  }

  for (int i = tid; i < 32*DD; i += 256){
    int tl = i >> 7, d = i & 127;
    ypre[((size_t)(b*TT + t0 + tl))*DD + d] =
        a_W[(size_t)d*(NUM_C + DD) + sQ[tl]] * (float)sR[tl] + a_b[d];
  }
}

// ---------------------------------------------------------------------------
// Kernel A2: exact match search (unchanged, proven).
// ---------------------------------------------------------------------------
__global__ __launch_bounds__(512) void kMatch(
    const ull* __restrict__ keyLo, const ull* __restrict__ keyHi, int* __restrict__ prevA)
{
  const int b = blockIdx.x, i = threadIdx.x;
  __shared__ ull slo[TT];
  __shared__ ull shi[TT];
  slo[i] = keyLo[b*TT + i];
  shi[i] = keyHi[b*TT + i];
  __syncthreads();
  const ull mylo = slo[i], myhi = shi[i];
  int found = -1;
  for (int j = i - 1; j >= 0; j--){
    if (slo[j] == mylo && shi[j] == myhi){ found = j; break; }
  }
  prevA[b*TT + i] = found;
}

// ---------------------------------------------------------------------------
// Kernel B (R6): memory recurrence. 8-lane groups (group g owns outputs
// 2g, 2g+1; lane sub owns k-slice [16*sub,+16) and m-slice [8*sub,+8)).
// Reductions via PROVEN __shfl_xor butterfly (no row_shr/row_shl DPP).
// wcur as 2xb128 from zero-padded sW8. Zero per-step global traffic.
// ---------------------------------------------------------------------------
__global__ __launch_bounds__(512, 2) void kMem(
    const float* __restrict__ wAll, const float* __restrict__ fpre, const float* __restrict__ ypre,
    const float* __restrict__ f_W, const float* __restrict__ a_W,
    const float* __restrict__ e_W, const float* __restrict__ e_b,
    const float* __restrict__ add_W, const float* __restrict__ add_b,
    const float* __restrict__ Mv0, float* __restrict__ fAll)
{
  const int b = blockIdx.x, tid = threadIdx.x;
  const int g = tid >> 3, sub = tid & 7;
  const int dd0 = 2*g;
  const int ks = sub*16;
  const int ms = sub*8;

  float mv0[8], mv1[8];
  #pragma unroll
  for (int i = 0; i < 8; i++){
    int m = ms + i;
    mv0[i] = (m < MM) ? Mv0[(size_t)m*DD + dd0]     : 0.f;
    mv1[i] = (m < MM) ? Mv0[(size_t)m*DD + dd0 + 1] : 0.f;
  }
  float wf[2][16], wa[2][16], we[2][16], wd[2][16];
  #pragma unroll
  for (int c = 0; c < 2; c++){
    const int dd = dd0 + c;
    const float4* p;
    p = reinterpret_cast<const float4*>(&f_W[dd*256 + ks]);
    #pragma unroll
    for (int i = 0; i < 4; i++){ float4 v = p[i]; wf[c][4*i]=v.x; wf[c][4*i+1]=v.y; wf[c][4*i+2]=v.z; wf[c][4*i+3]=v.w; }
    p = reinterpret_cast<const float4*>(&a_W[(size_t)dd*(NUM_C + DD) + NUM_C + ks]);
    #pragma unroll
    for (int i = 0; i < 4; i++){ float4 v = p[i]; wa[c][4*i]=v.x; wa[c][4*i+1]=v.y; wa[c][4*i+2]=v.z; wa[c][4*i+3]=v.w; }
    p = reinterpret_cast<const float4*>(&e_W[dd*DD + ks]);
    #pragma unroll
    for (int i = 0; i < 4; i++){ float4 v = p[i]; we[c][4*i]=v.x; we[c][4*i+1]=v.y; we[c][4*i+2]=v.z; we[c][4*i+3]=v.w; }
    p = reinterpret_cast<const float4*>(&add_W[dd*DD + ks]);
    #pragma unroll
    for (int i = 0; i < 4; i++){ float4 v = p[i]; wd[c][4*i]=v.x; wd[c][4*i+1]=v.y; wd[c][4*i+2]=v.z; wd[c][4*i+3]=v.w; }
  }
  const float ebv0 = e_b[dd0],   ebv1 = e_b[dd0+1];
  const float adb0 = add_b[dd0], adb1 = add_b[dd0+1];

  __shared__ __align__(16) float bufR[DD];
  __shared__ __align__(16) float bufF[DD];
  __shared__ __align__(16) float bufY[DD];
  __shared__ __align__(16) float sW8[8*64];   // zero-padded wAll chunk
  __shared__ __align__(16) float sF8[8*128];
  __shared__ __align__(16) float sY8[8*128];
  __shared__ __align__(16) float fO8[8*128];

  const size_t base = (size_t)b*TT;

  for (int t = 0; t < TT; t++){
    const int tc = t & 7;
    if (tc == 0){
      if (t){
        if (tid < 256){
          float4 v = reinterpret_cast<const float4*>(fO8)[tid];
          reinterpret_cast<float4*>(&fAll[(base + t - 8)*DD])[tid] = v;
        }
      }
      if (tid < 256){
        float4 v = reinterpret_cast<const float4*>(&fpre[(base + t)*DD])[tid];
        reinterpret_cast<float4*>(sF8)[tid] = v;
      } else {
        float4 v = reinterpret_cast<const float4*>(&ypre[(base + t)*DD])[tid - 256];
        reinterpret_cast<float4*>(sY8)[tid - 256] = v;
      }
      {
        int rr = tid >> 6, mm = tid & 63;
        sW8[tid] = (mm < MM) ? wAll[(base + t + rr)*MM + mm] : 0.f;
      }
      __syncthreads();   // R
    }

    // wcur: 8 floats (2 b128), zeros for m >= 50
    float wcur[8];
    {
      const float4* wp = reinterpret_cast<const float4*>(&sW8[tc*64 + ms]);
      float4 w0 = wp[0], w1 = wp[1];
      wcur[0]=w0.x; wcur[1]=w0.y; wcur[2]=w0.z; wcur[3]=w0.w;
      wcur[4]=w1.x; wcur[5]=w1.y; wcur[6]=w1.z; wcur[7]=w1.w;
    }

    // ---- stage 1: read[dd] = sum_m w[m]*Mv[m][dd] ----
    {
      float r0 = 0.f, r1 = 0.f;
      #pragma unroll
      for (int i = 0; i < 8; i++){ r0 += wcur[i]*mv0[i]; r1 += wcur[i]*mv1[i]; }
      r0 = sum8_(r0); r1 = sum8_(r1);
      if (sub == 0) *reinterpret_cast<float2*>(&bufR[dd0]) = make_float2(r0, r1);
    }
    __syncthreads();   // A

    // ---- stage 2: f = tanh(read @ f_Wr.T + fpre) ----
    {
      const float4* x4 = reinterpret_cast<const float4*>(&bufR[ks]);
      float4 xa = x4[0], xb = x4[1], xc = x4[2], xd = x4[3];
      float f0 = sum8_(dot16_(xa, xb, xc, xd, wf[0]));
      float f1 = sum8_(dot16_(xa, xb, xc, xd, wf[1]));
      if (sub == 0){
        float2 fp = *reinterpret_cast<const float2*>(&sF8[tc*128 + dd0]);
        float fv0 = tanhf(f0 + fp.x), fv1 = tanhf(f1 + fp.y);
        *reinterpret_cast<float2*>(&bufF[dd0])          = make_float2(fv0, fv1);
        *reinterpret_cast<float2*>(&fO8[tc*128 + dd0])  = make_float2(fv0, fv1);
      }
    }
    __syncthreads();   // B

    // ---- stage 3: y = ypre + f @ a_Wf.T ----
    {
      const float4* x4 = reinterpret_cast<const float4*>(&bufF[ks]);
      float4 xa = x4[0], xb = x4[1], xc = x4[2], xd = x4[3];
      float y0 = sum8_(dot16_(xa, xb, xc, xd, wa[0]));
      float y1 = sum8_(dot16_(xa, xb, xc, xd, wa[1]));
      if (sub == 0){
        float2 yp = *reinterpret_cast<const float2*>(&sY8[tc*128 + dd0]);
        *reinterpret_cast<float2*>(&bufY[dd0]) = make_float2(y0 + yp.x, y1 + yp.y);
      }
    }
    __syncthreads();   // C

    // ---- stage 4: e,a (all lanes get totals via butterfly) + Mv update ----
    {
      const float4* x4 = reinterpret_cast<const float4*>(&bufY[ks]);
      float4 xa = x4[0], xb = x4[1], xc = x4[2], xd = x4[3];
      float e0 = sum8_(dot16_(xa, xb, xc, xd, we[0]));
      float e1 = sum8_(dot16_(xa, xb, xc, xd, we[1]));
      float a0 = sum8_(dot16_(xa, xb, xc, xd, wd[0]));
      float a1 = sum8_(dot16_(xa, xb, xc, xd, wd[1]));
      float ed0 = sigmoidf_(e0 + ebv0), ed1 = sigmoidf_(e1 + ebv1);
      float ad0 = tanhf(a0 + adb0),     ad1 = tanhf(a1 + adb1);
      #pragma unroll
      for (int i = 0; i < 8; i++){
        float wv = wcur[i];
        mv0[i] = mv0[i]*(1.f - wv*ed0) + wv*ad0;
        mv1[i] = mv1[i]*(1.f - wv*ed1) + wv*ad1;
      }
    }
  }

  __syncthreads();
  if (tid < 256){
    float4 v = reinterpret_cast<const float4*>(fO8)[tid];
    reinterpret_cast<float4*>(&fAll[(base + TT - 8)*DD])[tid] = v;
  }
}

// ---------------------------------------------------------------------------
// Kernel D: gpre GEMM, cell-major output: gpre[row*512 + cell*4 + gate].
// ---------------------------------------------------------------------------
__global__ __launch_bounds__(256) void kGate(
    const float* __restrict__ fAll, const float* __restrict__ Wih,
    const float* __restrict__ bih, const float* __restrict__ bhh,
    float* __restrict__ gpre)
{
  const int jt = blockIdx.x;
  const int rt = blockIdx.y;
  const int tid = threadIdx.x;
  __shared__ float sW[64*129];
  __shared__ float sF[32*129];
  for (int i = tid; i < 64*128; i += 256){
    int jj = i >> 7, k = i & 127;
    sW[jj*129 + k] = Wih[(size_t)(jt*64 + jj)*128 + k];
  }
  for (int i = tid; i < 32*128; i += 256){
    int rr = i >> 7, k = i & 127;
    sF[rr*129 + k] = fAll[(size_t)(rt*32 + rr)*128 + k];
  }
  __syncthreads();
  const int jq = tid & 31, rq = tid >> 5;
  float acc[4][2];
  #pragma unroll
  for (int a = 0; a < 4; a++){ acc[a][0] = 0.f; acc[a][1] = 0.f; }
  for (int k = 0; k < 128; k++){
    float fv[4], wv[2];
    #pragma unroll
    for (int a = 0; a < 4; a++) fv[a] = sF[(rq*4 + a)*129 + k];
    wv[0] = sW[(jq*2 + 0)*129 + k];
    wv[1] = sW[(jq*2 + 1)*129 + k];
    #pragma unroll
    for (int a = 0; a < 4; a++){ acc[a][0] += fv[a]*wv[0]; acc[a][1] += fv[a]*wv[1]; }
  }
  #pragma unroll
  for (int a = 0; a < 4; a++){
    int rowi = rt*32 + rq*4 + a;
    #pragma unroll
    for (int c = 0; c < 2; c++){
      int j = jt*64 + jq*2 + c;           // gate-major: gate = j>>7, cell = j&127
      int cell = j & 127, gt = j >> 7;
      gpre[(size_t)rowi*512 + cell*4 + gt] = acc[a][c] + bih[j] + bhh[j];
    }
  }
}

// ---------------------------------------------------------------------------
// Kernel C (R6): LSTM — VERBATIM round-4 proven kernel (quad layout,
// quadSum_ DPP, per-step global Hh/Ch write + skip prefetch) with ONE delta:
// gpre is cell-major, so gate preacts are a single b128 read.
// ---------------------------------------------------------------------------
__global__ __launch_bounds__(512, 2) void kLstm(
    const float* __restrict__ gpre, const int* __restrict__ prevA,
    const float* __restrict__ Whh,
    float* __restrict__ Hh, float* __restrict__ Ch)
{
  const int b = blockIdx.x, tid = threadIdx.x;
  const int jo = tid >> 2, kc = tid & 3;
  const int wslot = (jo >> 5)*36 + (jo & 31);

  float whh[4][32];
  #pragma unroll
  for (int g = 0; g < 4; g++){
    const float4* W4 = reinterpret_cast<const float4*>(&Whh[(size_t)(g*128 + jo)*128 + kc*32]);
    #pragma unroll
    for (int i = 0; i < 8; i++){
      float4 v = W4[i];
      whh[g][4*i] = v.x; whh[g][4*i+1] = v.y; whh[g][4*i+2] = v.z; whh[g][4*i+3] = v.w;
    }
  }

  __shared__ __align__(16) float xh[2][144];
  __shared__ __align__(16) float gbuf[2][8*512];
  __shared__ int spv[TT];

  const size_t base = (size_t)b*TT;
  float4 gr0, gr1;
  {
    const float4* g0 = reinterpret_cast<const float4*>(&gpre[base*512]);
    float4 a = g0[tid*2], c = g0[tid*2+1];
    float4* gb4 = reinterpret_cast<float4*>(gbuf[0]);
    gb4[tid*2] = a; gb4[tid*2+1] = c;
    const float4* g1 = reinterpret_cast<const float4*>(&gpre[(base + 8)*512]);
    gr0 = g1[tid*2]; gr1 = g1[tid*2+1];
    spv[tid] = prevA[base + tid];
    if (tid < DD) xh[0][(tid >> 5)*36 + (tid & 31)] = 0.f;
  }
  __syncthreads();

  float cin_cur = 0.f;

  for (int t = 0; t < TT; t++){
    const int tc = t & 7, p = t & 1, pc = (t >> 3) & 1;
    if (tc == 0 && t){
      __syncthreads();
      {
        float4* gb4 = reinterpret_cast<float4*>(gbuf[pc]);
        gb4[tid*2] = gr0; gb4[tid*2+1] = gr1;
      }
      if (t + 8 < TT){
        const float4* gp4 = reinterpret_cast<const float4*>(&gpre[(base + t + 8)*512]);
        gr0 = gp4[tid*2]; gr1 = gp4[tid*2+1];
      }
      __syncthreads();
    } else if (t) {
      __syncthreads();
    }

    const size_t row = base + t;

    // early prefetch of skip state for t+1 (consumed at end of this step)
    int pv2 = -1; float preH = 0.f, preC = 0.f;
    if (t + 1 < TT){
      pv2 = spv[t + 1];
      if (pv2 >= 0 && pv2 < t){
        preH = Hh[(base + pv2)*DD + jo];
        preC = Ch[(base + pv2)*DD + jo];
      }
    }

    // gate pre-activations: one b128 (cell-major gpre)
    const float4 gp = *reinterpret_cast<const float4*>(&gbuf[pc][tc*512 + 4*jo]);

    // gates matvec over K-slice
    float a0=0.f,a1=0.f,a2=0.f,a3=0.f;
    {
      const float4* x4 = reinterpret_cast<const float4*>(&xh[p][kc*36]);
      #pragma unroll
      for (int i = 0; i < 8; i++){
        float4 xv = x4[i];
        a0 += xv.x*whh[0][4*i]; a0 += xv.y*whh[0][4*i+1]; a0 += xv.z*whh[0][4*i+2]; a0 += xv.w*whh[0][4*i+3];
        a1 += xv.x*whh[1][4*i]; a1 += xv.y*whh[1][4*i+1]; a1 += xv.z*whh[1][4*i+2]; a1 += xv.w*whh[1][4*i+3];
        a2 += xv.x*whh[2][4*i]; a2 += xv.y*whh[2][4*i+1]; a2 += xv.z*whh[2][4*i+2]; a2 += xv.w*whh[2][4*i+3];
        a3 += xv.x*whh[3][4*i]; a3 += xv.y*whh[3][4*i+1]; a3 += xv.z*whh[3][4*i+2]; a3 += xv.w*whh[3][4*i+3];
      }
    }
    a0 = quadSum_(a0); a1 = quadSum_(a1); a2 = quadSum_(a2); a3 = quadSum_(a3);

    const float ig = gp.x + a0, fg = gp.y + a1, gg = gp.z + a2, og = gp.w + a3;
    const float cn = sigmoidf_(fg)*cin_cur + sigmoidf_(ig)*tanhf(gg);
    const float hn = sigmoidf_(og)*tanhf(cn);

    if (kc == 0){
      Hh[row*DD + jo] = hn;
      Ch[row*DD + jo] = cn;
    }

    // select inputs for t+1, publish h_in to the other xh buffer
    float hin_n, cin_n;
    if (pv2 < 0 || pv2 >= t){ hin_n = hn; cin_n = cn; }       // carry (pv2==-1 or pv2==t)
    else                     { hin_n = preH; cin_n = preC; }   // skip (prefetched)
    if (kc == 0) xh[1 - p][wslot] = hin_n;
    cin_cur = cin_n;
  }
}

// ---------------------------------------------------------------------------
// Kernel E: output head (unchanged, proven).
// ---------------------------------------------------------------------------
__global__ __launch_bounds__(256) void kOut(
    const float* __restrict__ Hh, const float* __restrict__ p_W,
    const float* __restrict__ p_b, float* __restrict__ out)
{
  const int row = blockIdx.x*16 + (threadIdx.x >> 4);
  const int l = threadIdx.x & 15;
  const float4* h4 = reinterpret_cast<const float4*>(&Hh[(size_t)row*DD + l*8]);
  const float4* w4 = reinterpret_cast<const float4*>(&p_W[l*8]);
  float4 ha = h4[0], hb = h4[1], wa = w4[0], wb = w4[1];
  float s = ha.x*wa.x + ha.y*wa.y + ha.z*wa.z + ha.w*wa.w
          + hb.x*wb.x + hb.y*wb.y + hb.z*wb.z + hb.w*wb.w;
  s += __shfl_xor(s, 1); s += __shfl_xor(s, 2);
  s += __shfl_xor(s, 4); s += __shfl_xor(s, 8);
  if (l == 0) out[row] = sigmoidf_(s + p_b[0]);
}

// ---------------------------------------------------------------------------
// Launch.
// ---------------------------------------------------------------------------
extern "C" void kernel_launch(void* const* d_in, const int* in_sizes, int n_in,
                              void* d_out, int out_size, void* d_ws, size_t ws_size,
                              hipStream_t stream) {
  const int*   q     = (const int*)  d_in[0];
  const int*   r     = (const int*)  d_in[1];
  const float* k_emb = (const float*)d_in[2];
  const float* Mk    = (const float*)d_in[3];
  const float* Mv0   = (const float*)d_in[4];
  const float* f_W   = (const float*)d_in[5];
  const float* f_b   = (const float*)d_in[6];
  const float* a_W   = (const float*)d_in[7];
  const float* a_b   = (const float*)d_in[8];
  const float* e_W   = (const float*)d_in[9];
  const float* e_b   = (const float*)d_in[10];
  const float* add_W = (const float*)d_in[11];
  const float* add_b = (const float*)d_in[12];
  const float* Wih   = (const float*)d_in[13];
  const float* Whh   = (const float*)d_in[14];
  const float* bih   = (const float*)d_in[15];
  const float* bhh   = (const float*)d_in[16];
  const float* p_W   = (const float*)d_in[17];
  const float* p_b   = (const float*)d_in[18];
  float* out = (float*)d_out;

  char* ws = (char*)d_ws;
  size_t off = 0;
  auto alloc = [&](size_t bytes) -> char* {
    char* p = ws + off;
    off += (bytes + 255) & ~(size_t)255;
    return p;
  };
  float* wAll  = (float*)alloc((size_t)BB*TT*MM*4);
  float* fpre  = (float*)alloc((size_t)BB*TT*DD*4);
  float* ypre  = (float*)alloc((size_t)BB*TT*DD*4);
  float* fAll  = (float*)alloc((size_t)BB*TT*DD*4);
  float* gpre  = (float*)alloc((size_t)BB*TT*512*4);
  float* Hh    = (float*)alloc((size_t)BB*TT*DD*4);
  float* Ch    = (float*)alloc((size_t)BB*TT*DD*4);
  ull*   keyLo = (ull*)  alloc((size_t)BB*TT*8);
  ull*   keyHi = (ull*)  alloc((size_t)BB*TT*8);
  int*   prevA = (int*)  alloc((size_t)BB*TT*4);
  (void)ws_size; (void)in_sizes; (void)n_in; (void)out_size;

  kPre  <<<dim3(16, 32), 256, 0, stream>>>(q, r, k_emb, Mk, f_W, f_b, a_W, a_b,
                                           wAll, keyLo, keyHi, fpre, ypre);
  kMatch<<<32, 512, 0, stream>>>(keyLo, keyHi, prevA);
  kMem  <<<32, 512, 0, stream>>>(wAll, fpre, ypre, f_W, a_W, e_W, e_b, add_W, add_b,
                                 Mv0, fAll);
  kGate <<<dim3(8, 512), 256, 0, stream>>>(fAll, Wih, bih, bhh, gpre);
  kLstm <<<32, 512, 0, stream>>>(gpre, prevA, Whh, Hh, Ch);
  kOut  <<<(BB*TT)/16, 256, 0, stream>>>(Hh, p_W, p_b, out);
}

// Round 7
// 1875.610 us; speedup vs baseline: 1.0066x; 1.0066x over previous
//
#include <hip/hip_runtime.h>
#include <cstdint>
#include <cstddef>

// Problem constants
#define NUM_C 4096
#define BB 32
#define TT 512
#define DD 128
#define MM 50

using ull = unsigned long long;

__device__ __forceinline__ float sigmoidf_(float x){ return 1.0f/(1.0f + expf(-x)); }

// Quad reduction via DPP (VALU pipe) — PROVEN (R4/R6).
__device__ __forceinline__ float quadSum_(float v){
  int t = __builtin_amdgcn_update_dpp(0, __float_as_int(v), 0xB1, 0xF, 0xF, true);
  v += __int_as_float(t);
  t = __builtin_amdgcn_update_dpp(0, __float_as_int(v), 0x4E, 0xF, 0xF, true);
  v += __int_as_float(t);
  return v;
}

// 8-lane butterfly via shfl_xor (proven; all 8 lanes get the total)
__device__ __forceinline__ float sum8_(float v){
  v += __shfl_xor(v, 1);
  v += __shfl_xor(v, 2);
  v += __shfl_xor(v, 4);
  return v;
}

__device__ __forceinline__ float dot16_(const float4 xa, const float4 xb,
                                        const float4 xc, const float4 xd,
                                        const float* w){
  float s0 = xa.x*w[0]  + xa.y*w[1]  + xa.z*w[2]  + xa.w*w[3];
  float s1 = xb.x*w[4]  + xb.y*w[5]  + xb.z*w[6]  + xb.w*w[7];
  float s2 = xc.x*w[8]  + xc.y*w[9]  + xc.z*w[10] + xc.w*w[11];
  float s3 = xd.x*w[12] + xd.y*w[13] + xd.z*w[14] + xd.w*w[15];
  return (s0+s1)+(s2+s3);
}

// Swizzled slot for the 128-float activation buffers: slice stride 20 floats
// -> the 8 subs' b128 reads cover all 32 banks disjointly (zero conflicts).
#define SL(d) ((((d) >> 4) * 20) + ((d) & 15))

// ---------------------------------------------------------------------------
// Kernel A: parallel precompute (unchanged, proven).
// ---------------------------------------------------------------------------
__global__ __launch_bounds__(256) void kPre(
    const int* __restrict__ q, const int* __restrict__ r,
    const float* __restrict__ k_emb, const float* __restrict__ Mk,
    const float* __restrict__ f_W, const float* __restrict__ f_b,
    const float* __restrict__ a_W, const float* __restrict__ a_b,
    float* __restrict__ wAll, ull* __restrict__ keyLo, ull* __restrict__ keyHi,
    float* __restrict__ fpre, float* __restrict__ ypre)
{
  const int b = blockIdx.y, t0 = blockIdx.x * 32, tid = threadIdx.x;
  __shared__ __align__(16) float sK[32*129];
  __shared__ int sQ[32];
  __shared__ int sR[32];
  __shared__ union UU {
    struct { float sMk[MM*129]; double sZ[32*MM]; } p2;
    float sW2[128*65];
  } u;

  if (tid < 32){ sQ[tid] = q[b*TT + t0 + tid]; sR[tid] = r[b*TT + t0 + tid]; }
  __syncthreads();
  for (int i = tid; i < 32*128; i += 256){
    int tl = i >> 7, j = i & 127;
    sK[tl*129 + j] = k_emb[(size_t)sQ[tl]*DD + j];
  }
  for (int i = tid; i < MM*128; i += 256){
    int m = i >> 7, j = i & 127;
    u.p2.sMk[m*129 + j] = Mk[i];
  }
  __syncthreads();

  for (int idx = tid; idx < 32*MM; idx += 256){
    int tl = idx / MM, m = idx - tl*MM;
    double z = 0.0;
    for (int j = 0; j < DD; j++)
      z += (double)sK[tl*129 + j] * (double)u.p2.sMk[m*129 + j];
    u.p2.sZ[tl*MM + m] = z;
  }
  __syncthreads();

  {
    int tl = tid >> 3, l8 = tid & 7;
    double zmax = -1e300;
    for (int m = l8; m < MM; m += 8) zmax = fmax(zmax, u.p2.sZ[tl*MM + m]);
    for (int s = 1; s < 8; s <<= 1) zmax = fmax(zmax, __shfl_xor(zmax, s));
    double se = 0.0;
    for (int m = l8; m < MM; m += 8){
      double e = exp(u.p2.sZ[tl*MM + m] - zmax);
      u.p2.sZ[tl*MM + m] = e;
      se += e;
    }
    for (int s = 1; s < 8; s <<= 1) se += __shfl_xor(se, s);
    double inv = 1.0 / se;
    ull klo = 0, khi = 0;
    for (int m = l8; m < MM; m += 8){
      double w = u.p2.sZ[tl*MM + m] * inv;
      wAll[((size_t)(b*TT + t0 + tl))*MM + m] = (float)w;
      double tw = fmin((w - 0.075)/(0.088 - 0.075), (1.0 - w)/(1.0 - 0.088));
      tw = fmax(tw, 0.0);
      ull iv = (tw >= 0.6) ? 2ull : ((tw >= 0.1) ? 1ull : 0ull);
      if (m < 32) klo |= iv << (2*m); else khi |= iv << (2*(m-32));
    }
    for (int s = 1; s < 8; s <<= 1){ klo |= __shfl_xor(klo, s); khi |= __shfl_xor(khi, s); }
    if (l8 == 0){ keyLo[b*TT + t0 + tl] = klo; keyHi[b*TT + t0 + tl] = khi; }
  }

  {
    const int dq = tid & 31, tq = tid >> 5;
    float acc[4][4];
    #pragma unroll
    for (int a = 0; a < 4; a++){ acc[a][0]=0.f; acc[a][1]=0.f; acc[a][2]=0.f; acc[a][3]=0.f; }
    for (int jh = 0; jh < 2; jh++){
      __syncthreads();
      for (int i = tid; i < 128*64; i += 256){
        int dd = i >> 6, jj = i & 63;
        u.sW2[dd*65 + jj] = f_W[dd*256 + 128 + jh*64 + jj];
      }
      __syncthreads();
      for (int jj = 0; jj < 64; jj++){
        float kv[4], wv[4];
        #pragma unroll
        for (int a = 0; a < 4; a++) kv[a] = sK[(tq*4 + a)*129 + jh*64 + jj];
        #pragma unroll
        for (int c = 0; c < 4; c++) wv[c] = u.sW2[(dq*4 + c)*65 + jj];
        #pragma unroll
        for (int a = 0; a < 4; a++){
          acc[a][0] += kv[a]*wv[0]; acc[a][1] += kv[a]*wv[1];
          acc[a][2] += kv[a]*wv[2]; acc[a][3] += kv[a]*wv[3];
        }
      }
    }
    #pragma unroll
    for (int a = 0; a < 4; a++){
      int tl = tq*4 + a;
      #pragma unroll
      for (int c = 0; c < 4; c++){
        int d = dq*4 + c;
        fpre[((size_t)(b*TT + t0 + tl))*DD + d] = acc[a][c] + f_b[d];
      }
    }
  }

  for (int i = tid; i < 32*DD; i += 256){
    int tl = i >> 7, d = i & 127;
    ypre[((size_t)(b*TT + t0 + tl))*DD + d] =
        a_W[(size_t)d*(NUM_C + DD) + sQ[tl]] * (float)sR[tl] + a_b[d];
  }
}

// ---------------------------------------------------------------------------
// Kernel A2: exact match search (unchanged, proven).
// ---------------------------------------------------------------------------
__global__ __launch_bounds__(512) void kMatch(
    const ull* __restrict__ keyLo, const ull* __restrict__ keyHi, int* __restrict__ prevA)
{
  const int b = blockIdx.x, i = threadIdx.x;
  __shared__ ull slo[TT];
  __shared__ ull shi[TT];
  slo[i] = keyLo[b*TT + i];
  shi[i] = keyHi[b*TT + i];
  __syncthreads();
  const ull mylo = slo[i], myhi = shi[i];
  int found = -1;
  for (int j = i - 1; j >= 0; j--){
    if (slo[j] == mylo && shi[j] == myhi){ found = j; break; }
  }
  prevA[b*TT + i] = found;
}

// ---------------------------------------------------------------------------
// Kernel B (R7): memory recurrence. 8-lane groups as R6, but the activation
// buffers use the 20-stride swizzle SL(d): sub's slice base sub*20 mod 32 =
// {0,20,8,28,16,4,24,12} -> b128 reads cover all 32 banks disjointly.
// ONLY delta vs R6 = the swizzle (conflict fix).
// ---------------------------------------------------------------------------
__global__ __launch_bounds__(512, 2) void kMem(
    const float* __restrict__ wAll, const float* __restrict__ fpre, const float* __restrict__ ypre,
    const float* __restrict__ f_W, const float* __restrict__ a_W,
    const float* __restrict__ e_W, const float* __restrict__ e_b,
    const float* __restrict__ add_W, const float* __restrict__ add_b,
    const float* __restrict__ Mv0, float* __restrict__ fAll)
{
  const int b = blockIdx.x, tid = threadIdx.x;
  const int g = tid >> 3, sub = tid & 7;
  const int dd0 = 2*g;
  const int ks = sub*16;
  const int ms = sub*8;
  const int slot0 = SL(dd0);          // swizzled write slot (dd0 even -> same slice)

  float mv0[8], mv1[8];
  #pragma unroll
  for (int i = 0; i < 8; i++){
    int m = ms + i;
    mv0[i] = (m < MM) ? Mv0[(size_t)m*DD + dd0]     : 0.f;
    mv1[i] = (m < MM) ? Mv0[(size_t)m*DD + dd0 + 1] : 0.f;
  }
  float wf[2][16], wa[2][16], we[2][16], wd[2][16];
  #pragma unroll
  for (int c = 0; c < 2; c++){
    const int dd = dd0 + c;
    const float4* p;
    p = reinterpret_cast<const float4*>(&f_W[dd*256 + ks]);
    #pragma unroll
    for (int i = 0; i < 4; i++){ float4 v = p[i]; wf[c][4*i]=v.x; wf[c][4*i+1]=v.y; wf[c][4*i+2]=v.z; wf[c][4*i+3]=v.w; }
    p = reinterpret_cast<const float4*>(&a_W[(size_t)dd*(NUM_C + DD) + NUM_C + ks]);
    #pragma unroll
    for (int i = 0; i < 4; i++){ float4 v = p[i]; wa[c][4*i]=v.x; wa[c][4*i+1]=v.y; wa[c][4*i+2]=v.z; wa[c][4*i+3]=v.w; }
    p = reinterpret_cast<const float4*>(&e_W[dd*DD + ks]);
    #pragma unroll
    for (int i = 0; i < 4; i++){ float4 v = p[i]; we[c][4*i]=v.x; we[c][4*i+1]=v.y; we[c][4*i+2]=v.z; we[c][4*i+3]=v.w; }
    p = reinterpret_cast<const float4*>(&add_W[dd*DD + ks]);
    #pragma unroll
    for (int i = 0; i < 4; i++){ float4 v = p[i]; wd[c][4*i]=v.x; wd[c][4*i+1]=v.y; wd[c][4*i+2]=v.z; wd[c][4*i+3]=v.w; }
  }
  const float ebv0 = e_b[dd0],   ebv1 = e_b[dd0+1];
  const float adb0 = add_b[dd0], adb1 = add_b[dd0+1];

  __shared__ __align__(16) float bufR[160];   // swizzled (8 slices x 20)
  __shared__ __align__(16) float bufF[160];
  __shared__ __align__(16) float bufY[160];
  __shared__ __align__(16) float sW8[8*64];   // zero-padded wAll chunk
  __shared__ __align__(16) float sF8[8*128];
  __shared__ __align__(16) float sY8[8*128];
  __shared__ __align__(16) float fO8[8*128];

  const size_t base = (size_t)b*TT;

  for (int t = 0; t < TT; t++){
    const int tc = t & 7;
    if (tc == 0){
      if (t){
        if (tid < 256){
          float4 v = reinterpret_cast<const float4*>(fO8)[tid];
          reinterpret_cast<float4*>(&fAll[(base + t - 8)*DD])[tid] = v;
        }
      }
      if (tid < 256){
        float4 v = reinterpret_cast<const float4*>(&fpre[(base + t)*DD])[tid];
        reinterpret_cast<float4*>(sF8)[tid] = v;
      } else {
        float4 v = reinterpret_cast<const float4*>(&ypre[(base + t)*DD])[tid - 256];
        reinterpret_cast<float4*>(sY8)[tid - 256] = v;
      }
      {
        int rr = tid >> 6, mm = tid & 63;
        sW8[tid] = (mm < MM) ? wAll[(base + t + rr)*MM + mm] : 0.f;
      }
      __syncthreads();   // R
    }

    // wcur: 8 floats (2 b128), zeros for m >= 50
    float wcur[8];
    {
      const float4* wp = reinterpret_cast<const float4*>(&sW8[tc*64 + ms]);
      float4 w0 = wp[0], w1 = wp[1];
      wcur[0]=w0.x; wcur[1]=w0.y; wcur[2]=w0.z; wcur[3]=w0.w;
      wcur[4]=w1.x; wcur[5]=w1.y; wcur[6]=w1.z; wcur[7]=w1.w;
    }

    // ---- stage 1: read[dd] = sum_m w[m]*Mv[m][dd] ----
    {
      float r0 = 0.f, r1 = 0.f;
      #pragma unroll
      for (int i = 0; i < 8; i++){ r0 += wcur[i]*mv0[i]; r1 += wcur[i]*mv1[i]; }
      r0 = sum8_(r0); r1 = sum8_(r1);
      if (sub == 0) *reinterpret_cast<float2*>(&bufR[slot0]) = make_float2(r0, r1);
    }
    __syncthreads();   // A

    // ---- stage 2: f = tanh(read @ f_Wr.T + fpre) ----
    {
      const float4* x4 = reinterpret_cast<const float4*>(&bufR[sub*20]);
      float4 xa = x4[0], xb = x4[1], xc = x4[2], xd = x4[3];
      float f0 = sum8_(dot16_(xa, xb, xc, xd, wf[0]));
      float f1 = sum8_(dot16_(xa, xb, xc, xd, wf[1]));
      if (sub == 0){
        float2 fp = *reinterpret_cast<const float2*>(&sF8[tc*128 + dd0]);
        float fv0 = tanhf(f0 + fp.x), fv1 = tanhf(f1 + fp.y);
        *reinterpret_cast<float2*>(&bufF[slot0])        = make_float2(fv0, fv1);
        *reinterpret_cast<float2*>(&fO8[tc*128 + dd0])  = make_float2(fv0, fv1);
      }
    }
    __syncthreads();   // B

    // ---- stage 3: y = ypre + f @ a_Wf.T ----
    {
      const float4* x4 = reinterpret_cast<const float4*>(&bufF[sub*20]);
      float4 xa = x4[0], xb = x4[1], xc = x4[2], xd = x4[3];
      float y0 = sum8_(dot16_(xa, xb, xc, xd, wa[0]));
      float y1 = sum8_(dot16_(xa, xb, xc, xd, wa[1]));
      if (sub == 0){
        float2 yp = *reinterpret_cast<const float2*>(&sY8[tc*128 + dd0]);
        *reinterpret_cast<float2*>(&bufY[slot0]) = make_float2(y0 + yp.x, y1 + yp.y);
      }
    }
    __syncthreads();   // C

    // ---- stage 4: e,a (all lanes get totals) + Mv update (no barrier) ----
    {
      const float4* x4 = reinterpret_cast<const float4*>(&bufY[sub*20]);
      float4 xa = x4[0], xb = x4[1], xc = x4[2], xd = x4[3];
      float e0 = sum8_(dot16_(xa, xb, xc, xd, we[0]));
      float e1 = sum8_(dot16_(xa, xb, xc, xd, we[1]));
      float a0 = sum8_(dot16_(xa, xb, xc, xd, wd[0]));
      float a1 = sum8_(dot16_(xa, xb, xc, xd, wd[1]));
      float ed0 = sigmoidf_(e0 + ebv0), ed1 = sigmoidf_(e1 + ebv1);
      float ad0 = tanhf(a0 + adb0),     ad1 = tanhf(a1 + adb1);
      #pragma unroll
      for (int i = 0; i < 8; i++){
        float wv = wcur[i];
        mv0[i] = mv0[i]*(1.f - wv*ed0) + wv*ad0;
        mv1[i] = mv1[i]*(1.f - wv*ed1) + wv*ad1;
      }
    }
  }

  __syncthreads();
  if (tid < 256){
    float4 v = reinterpret_cast<const float4*>(fO8)[tid];
    reinterpret_cast<float4*>(&fAll[(base + TT - 8)*DD])[tid] = v;
  }
}

// ---------------------------------------------------------------------------
// Kernel D: gpre GEMM, cell-major output (unchanged from R6, proven).
// ---------------------------------------------------------------------------
__global__ __launch_bounds__(256) void kGate(
    const float* __restrict__ fAll, const float* __restrict__ Wih,
    const float* __restrict__ bih, const float* __restrict__ bhh,
    float* __restrict__ gpre)
{
  const int jt = blockIdx.x;
  const int rt = blockIdx.y;
  const int tid = threadIdx.x;
  __shared__ float sW[64*129];
  __shared__ float sF[32*129];
  for (int i = tid; i < 64*128; i += 256){
    int jj = i >> 7, k = i & 127;
    sW[jj*129 + k] = Wih[(size_t)(jt*64 + jj)*128 + k];
  }
  for (int i = tid; i < 32*128; i += 256){
    int rr = i >> 7, k = i & 127;
    sF[rr*129 + k] = fAll[(size_t)(rt*32 + rr)*128 + k];
  }
  __syncthreads();
  const int jq = tid & 31, rq = tid >> 5;
  float acc[4][2];
  #pragma unroll
  for (int a = 0; a < 4; a++){ acc[a][0] = 0.f; acc[a][1] = 0.f; }
  for (int k = 0; k < 128; k++){
    float fv[4], wv[2];
    #pragma unroll
    for (int a = 0; a < 4; a++) fv[a] = sF[(rq*4 + a)*129 + k];
    wv[0] = sW[(jq*2 + 0)*129 + k];
    wv[1] = sW[(jq*2 + 1)*129 + k];
    #pragma unroll
    for (int a = 0; a < 4; a++){ acc[a][0] += fv[a]*wv[0]; acc[a][1] += fv[a]*wv[1]; }
  }
  #pragma unroll
  for (int a = 0; a < 4; a++){
    int rowi = rt*32 + rq*4 + a;
    #pragma unroll
    for (int c = 0; c < 2; c++){
      int j = jt*64 + jq*2 + c;           // gate-major: gate = j>>7, cell = j&127
      int cell = j & 127, gt = j >> 7;
      gpre[(size_t)rowi*512 + cell*4 + gt] = acc[a][c] + bih[j] + bhh[j];
    }
  }
}

// ---------------------------------------------------------------------------
// Kernel C: LSTM (unchanged from R6, proven).
// ---------------------------------------------------------------------------
__global__ __launch_bounds__(512, 2) void kLstm(
    const float* __restrict__ gpre, const int* __restrict__ prevA,
    const float* __restrict__ Whh,
    float* __restrict__ Hh, float* __restrict__ Ch)
{
  const int b = blockIdx.x, tid = threadIdx.x;
  const int jo = tid >> 2, kc = tid & 3;
  const int wslot = (jo >> 5)*36 + (jo & 31);

  float whh[4][32];
  #pragma unroll
  for (int g = 0; g < 4; g++){
    const float4* W4 = reinterpret_cast<const float4*>(&Whh[(size_t)(g*128 + jo)*128 + kc*32]);
    #pragma unroll
    for (int i = 0; i < 8; i++){
      float4 v = W4[i];
      whh[g][4*i] = v.x; whh[g][4*i+1] = v.y; whh[g][4*i+2] = v.z; whh[g][4*i+3] = v.w;
    }
  }

  __shared__ __align__(16) float xh[2][144];
  __shared__ __align__(16) float gbuf[2][8*512];
  __shared__ int spv[TT];

  const size_t base = (size_t)b*TT;
  float4 gr0, gr1;
  {
    const float4* g0 = reinterpret_cast<const float4*>(&gpre[base*512]);
    float4 a = g0[tid*2], c = g0[tid*2+1];
    float4* gb4 = reinterpret_cast<float4*>(gbuf[0]);
    gb4[tid*2] = a; gb4[tid*2+1] = c;
    const float4* g1 = reinterpret_cast<const float4*>(&gpre[(base + 8)*512]);
    gr0 = g1[tid*2]; gr1 = g1[tid*2+1];
    spv[tid] = prevA[base + tid];
    if (tid < DD) xh[0][(tid >> 5)*36 + (tid & 31)] = 0.f;
  }
  __syncthreads();

  float cin_cur = 0.f;

  for (int t = 0; t < TT; t++){
    const int tc = t & 7, p = t & 1, pc = (t >> 3) & 1;
    if (tc == 0 && t){
      __syncthreads();
      {
        float4* gb4 = reinterpret_cast<float4*>(gbuf[pc]);
        gb4[tid*2] = gr0; gb4[tid*2+1] = gr1;
      }
      if (t + 8 < TT){
        const float4* gp4 = reinterpret_cast<const float4*>(&gpre[(base + t + 8)*512]);
        gr0 = gp4[tid*2]; gr1 = gp4[tid*2+1];
      }
      __syncthreads();
    } else if (t) {
      __syncthreads();
    }

    const size_t row = base + t;

    int pv2 = -1; float preH = 0.f, preC = 0.f;
    if (t + 1 < TT){
      pv2 = spv[t + 1];
      if (pv2 >= 0 && pv2 < t){
        preH = Hh[(base + pv2)*DD + jo];
        preC = Ch[(base + pv2)*DD + jo];
      }
    }

    const float4 gp = *reinterpret_cast<const float4*>(&gbuf[pc][tc*512 + 4*jo]);

    float a0=0.f,a1=0.f,a2=0.f,a3=0.f;
    {
      const float4* x4 = reinterpret_cast<const float4*>(&xh[p][kc*36]);
      #pragma unroll
      for (int i = 0; i < 8; i++){
        float4 xv = x4[i];
        a0 += xv.x*whh[0][4*i]; a0 += xv.y*whh[0][4*i+1]; a0 += xv.z*whh[0][4*i+2]; a0 += xv.w*whh[0][4*i+3];
        a1 += xv.x*whh[1][4*i]; a1 += xv.y*whh[1][4*i+1]; a1 += xv.z*whh[1][4*i+2]; a1 += xv.w*whh[1][4*i+3];
        a2 += xv.x*whh[2][4*i]; a2 += xv.y*whh[2][4*i+1]; a2 += xv.z*whh[2][4*i+2]; a2 += xv.w*whh[2][4*i+3];
        a3 += xv.x*whh[3][4*i]; a3 += xv.y*whh[3][4*i+1]; a3 += xv.z*whh[3][4*i+2]; a3 += xv.w*whh[3][4*i+3];
      }
    }
    a0 = quadSum_(a0); a1 = quadSum_(a1); a2 = quadSum_(a2); a3 = quadSum_(a3);

    const float ig = gp.x + a0, fg = gp.y + a1, gg = gp.z + a2, og = gp.w + a3;
    const float cn = sigmoidf_(fg)*cin_cur + sigmoidf_(ig)*tanhf(gg);
    const float hn = sigmoidf_(og)*tanhf(cn);

    if (kc == 0){
      Hh[row*DD + jo] = hn;
      Ch[row*DD + jo] = cn;
    }

    float hin_n, cin_n;
    if (pv2 < 0 || pv2 >= t){ hin_n = hn; cin_n = cn; }
    else                     { hin_n = preH; cin_n = preC; }
    if (kc == 0) xh[1 - p][wslot] = hin_n;
    cin_cur = cin_n;
  }
}

// ---------------------------------------------------------------------------
// Kernel E: output head (unchanged, proven).
// ---------------------------------------------------------------------------
__global__ __launch_bounds__(256) void kOut(
    const float* __restrict__ Hh, const float* __restrict__ p_W,
    const float* __restrict__ p_b, float* __restrict__ out)
{
  const int row = blockIdx.x*16 + (threadIdx.x >> 4);
  const int l = threadIdx.x & 15;
  const float4* h4 = reinterpret_cast<const float4*>(&Hh[(size_t)row*DD + l*8]);
  const float4* w4 = reinterpret_cast<const float4*>(&p_W[l*8]);
  float4 ha = h4[0], hb = h4[1], wa = w4[0], wb = w4[1];
  float s = ha.x*wa.x + ha.y*wa.y + ha.z*wa.z + ha.w*wa.w
          + hb.x*wb.x + hb.y*wb.y + hb.z*wb.z + hb.w*wb.w;
  s += __shfl_xor(s, 1); s += __shfl_xor(s, 2);
  s += __shfl_xor(s, 4); s += __shfl_xor(s, 8);
  if (l == 0) out[row] = sigmoidf_(s + p_b[0]);
}

// ---------------------------------------------------------------------------
// Launch.
// ---------------------------------------------------------------------------
extern "C" void kernel_launch(void* const* d_in, const int* in_sizes, int n_in,
                              void* d_out, int out_size, void* d_ws, size_t ws_size,
                              hipStream_t stream) {
  const int*   q     = (const int*)  d_in[0];
  const int*   r     = (const int*)  d_in[1];
  const float* k_emb = (const float*)d_in[2];
  const float* Mk    = (const float*)d_in[3];
  const float* Mv0   = (const float*)d_in[4];
  const float* f_W   = (const float*)d_in[5];
  const float* f_b   = (const float*)d_in[6];
  const float* a_W   = (const float*)d_in[7];
  const float* a_b   = (const float*)d_in[8];
  const float* e_W   = (const float*)d_in[9];
  const float* e_b   = (const float*)d_in[10];
  const float* add_W = (const float*)d_in[11];
  const float* add_b = (const float*)d_in[12];
  const float* Wih   = (const float*)d_in[13];
  const float* Whh   = (const float*)d_in[14];
  const float* bih   = (const float*)d_in[15];
  const float* bhh   = (const float*)d_in[16];
  const float* p_W   = (const float*)d_in[17];
  const float* p_b   = (const float*)d_in[18];
  float* out = (float*)d_out;

  char* ws = (char*)d_ws;
  size_t off = 0;
  auto alloc = [&](size_t bytes) -> char* {
    char* p = ws + off;
    off += (bytes + 255) & ~(size_t)255;
    return p;
  };
  float* wAll  = (float*)alloc((size_t)BB*TT*MM*4);
  float* fpre  = (float*)alloc((size_t)BB*TT*DD*4);
  float* ypre  = (float*)alloc((size_t)BB*TT*DD*4);
  float* fAll  = (float*)alloc((size_t)BB*TT*DD*4);
  float* gpre  = (float*)alloc((size_t)BB*TT*512*4);
  float* Hh    = (float*)alloc((size_t)BB*TT*DD*4);
  float* Ch    = (float*)alloc((size_t)BB*TT*DD*4);
  ull*   keyLo = (ull*)  alloc((size_t)BB*TT*8);
  ull*   keyHi = (ull*)  alloc((size_t)BB*TT*8);
  int*   prevA = (int*)  alloc((size_t)BB*TT*4);
  (void)ws_size; (void)in_sizes; (void)n_in; (void)out_size;

  kPre  <<<dim3(16, 32), 256, 0, stream>>>(q, r, k_emb, Mk, f_W, f_b, a_W, a_b,
                                           wAll, keyLo, keyHi, fpre, ypre);
  kMatch<<<32, 512, 0, stream>>>(keyLo, keyHi, prevA);
  kMem  <<<32, 512, 0, stream>>>(wAll, fpre, ypre, f_W, a_W, e_W, e_b, add_W, add_b,
                                 Mv0, fAll);
  kGate <<<dim3(8, 512), 256, 0, stream>>>(fAll, Wih, bih, bhh, gpre);
  kLstm <<<32, 512, 0, stream>>>(gpre, prevA, Whh, Hh, Ch);
  kOut  <<<(BB*TT)/16, 256, 0, stream>>>(Hh, p_W, p_b, out);
}

// Round 8
// 1847.685 us; speedup vs baseline: 1.0218x; 1.0151x over previous
//
#include <hip/hip_runtime.h>
#include <cstdint>
#include <cstddef>

// Problem constants
#define NUM_C 4096
#define BB 32
#define TT 512
#define DD 128
#define MM 50

using ull = unsigned long long;

__device__ __forceinline__ float sigmoidf_(float x){ return 1.0f/(1.0f + expf(-x)); }

// Quad reduction via DPP (VALU pipe) — PROVEN (R4/R6/R7).
__device__ __forceinline__ float quadSum_(float v){
  int t = __builtin_amdgcn_update_dpp(0, __float_as_int(v), 0xB1, 0xF, 0xF, true);
  v += __int_as_float(t);
  t = __builtin_amdgcn_update_dpp(0, __float_as_int(v), 0x4E, 0xF, 0xF, true);
  v += __int_as_float(t);
  return v;
}

// 8-lane reductions on the VALU pipe (DPP), replacing ds_swizzle-based shfl.
// row_shr:4 = 0x114 (lane i reads lane i+4), row_shl:4 = 0x104 (lane i reads
// lane i-4); masked-out lanes inherit the '0' old-value operand.
// Valid result on lanes sub<4 of each 8-group (we consume at sub==0):
__device__ __forceinline__ float red8lo_(float v){
  int t = __builtin_amdgcn_update_dpp(0, __float_as_int(v), 0x114, 0xF, 0xF, true);
  v += __int_as_float(t);   // lanes i += lanes i+4
  t = __builtin_amdgcn_update_dpp(0, __float_as_int(v), 0x4E, 0xF, 0xF, true);
  v += __int_as_float(t);   // quad xor2
  t = __builtin_amdgcn_update_dpp(0, __float_as_int(v), 0xB1, 0xF, 0xF, true);
  v += __int_as_float(t);   // quad xor1
  return v;
}
// Valid result on ALL 8 lanes of each 8-group:
__device__ __forceinline__ float red8all_(float v){
  int t = __builtin_amdgcn_update_dpp(0, __float_as_int(v), 0xB1, 0xF, 0xF, true);
  v += __int_as_float(t);   // xor1
  t = __builtin_amdgcn_update_dpp(0, __float_as_int(v), 0x4E, 0xF, 0xF, true);
  v += __int_as_float(t);   // xor2 -> every quad holds its quad-sum
  int a = __builtin_amdgcn_update_dpp(0, __float_as_int(v), 0x114, 0xF, 0x5, true); // banks 0,2: += lane+4
  int b = __builtin_amdgcn_update_dpp(0, __float_as_int(v), 0x104, 0xF, 0xA, true); // banks 1,3: += lane-4
  return v + __int_as_float(a) + __int_as_float(b);
}

__device__ __forceinline__ float dot16_(const float4 xa, const float4 xb,
                                        const float4 xc, const float4 xd,
                                        const float* w){
  float s0 = xa.x*w[0]  + xa.y*w[1]  + xa.z*w[2]  + xa.w*w[3];
  float s1 = xb.x*w[4]  + xb.y*w[5]  + xb.z*w[6]  + xb.w*w[7];
  float s2 = xc.x*w[8]  + xc.y*w[9]  + xc.z*w[10] + xc.w*w[11];
  float s3 = xd.x*w[12] + xd.y*w[13] + xd.z*w[14] + xd.w*w[15];
  return (s0+s1)+(s2+s3);
}

// Swizzled slot for the 128-float activation buffers: slice stride 20 floats
// -> the 8 subs' b128 reads cover all 32 banks disjointly (zero conflicts).
#define SL(d) ((((d) >> 4) * 20) + ((d) & 15))

// ---------------------------------------------------------------------------
// Kernel A: parallel precompute (unchanged, proven).
// ---------------------------------------------------------------------------
__global__ __launch_bounds__(256) void kPre(
    const int* __restrict__ q, const int* __restrict__ r,
    const float* __restrict__ k_emb, const float* __restrict__ Mk,
    const float* __restrict__ f_W, const float* __restrict__ f_b,
    const float* __restrict__ a_W, const float* __restrict__ a_b,
    float* __restrict__ wAll, ull* __restrict__ keyLo, ull* __restrict__ keyHi,
    float* __restrict__ fpre, float* __restrict__ ypre)
{
  const int b = blockIdx.y, t0 = blockIdx.x * 32, tid = threadIdx.x;
  __shared__ __align__(16) float sK[32*129];
  __shared__ int sQ[32];
  __shared__ int sR[32];
  __shared__ union UU {
    struct { float sMk[MM*129]; double sZ[32*MM]; } p2;
    float sW2[128*65];
  } u;

  if (tid < 32){ sQ[tid] = q[b*TT + t0 + tid]; sR[tid] = r[b*TT + t0 + tid]; }
  __syncthreads();
  for (int i = tid; i < 32*128; i += 256){
    int tl = i >> 7, j = i & 127;
    sK[tl*129 + j] = k_emb[(size_t)sQ[tl]*DD + j];
  }
  for (int i = tid; i < MM*128; i += 256){
    int m = i >> 7, j = i & 127;
    u.p2.sMk[m*129 + j] = Mk[i];
  }
  __syncthreads();

  for (int idx = tid; idx < 32*MM; idx += 256){
    int tl = idx / MM, m = idx - tl*MM;
    double z = 0.0;
    for (int j = 0; j < DD; j++)
      z += (double)sK[tl*129 + j] * (double)u.p2.sMk[m*129 + j];
    u.p2.sZ[tl*MM + m] = z;
  }
  __syncthreads();

  {
    int tl = tid >> 3, l8 = tid & 7;
    double zmax = -1e300;
    for (int m = l8; m < MM; m += 8) zmax = fmax(zmax, u.p2.sZ[tl*MM + m]);
    for (int s = 1; s < 8; s <<= 1) zmax = fmax(zmax, __shfl_xor(zmax, s));
    double se = 0.0;
    for (int m = l8; m < MM; m += 8){
      double e = exp(u.p2.sZ[tl*MM + m] - zmax);
      u.p2.sZ[tl*MM + m] = e;
      se += e;
    }
    for (int s = 1; s < 8; s <<= 1) se += __shfl_xor(se, s);
    double inv = 1.0 / se;
    ull klo = 0, khi = 0;
    for (int m = l8; m < MM; m += 8){
      double w = u.p2.sZ[tl*MM + m] * inv;
      wAll[((size_t)(b*TT + t0 + tl))*MM + m] = (float)w;
      double tw = fmin((w - 0.075)/(0.088 - 0.075), (1.0 - w)/(1.0 - 0.088));
      tw = fmax(tw, 0.0);
      ull iv = (tw >= 0.6) ? 2ull : ((tw >= 0.1) ? 1ull : 0ull);
      if (m < 32) klo |= iv << (2*m); else khi |= iv << (2*(m-32));
    }
    for (int s = 1; s < 8; s <<= 1){ klo |= __shfl_xor(klo, s); khi |= __shfl_xor(khi, s); }
    if (l8 == 0){ keyLo[b*TT + t0 + tl] = klo; keyHi[b*TT + t0 + tl] = khi; }
  }

  {
    const int dq = tid & 31, tq = tid >> 5;
    float acc[4][4];
    #pragma unroll
    for (int a = 0; a < 4; a++){ acc[a][0]=0.f; acc[a][1]=0.f; acc[a][2]=0.f; acc[a][3]=0.f; }
    for (int jh = 0; jh < 2; jh++){
      __syncthreads();
      for (int i = tid; i < 128*64; i += 256){
        int dd = i >> 6, jj = i & 63;
        u.sW2[dd*65 + jj] = f_W[dd*256 + 128 + jh*64 + jj];
      }
      __syncthreads();
      for (int jj = 0; jj < 64; jj++){
        float kv[4], wv[4];
        #pragma unroll
        for (int a = 0; a < 4; a++) kv[a] = sK[(tq*4 + a)*129 + jh*64 + jj];
        #pragma unroll
        for (int c = 0; c < 4; c++) wv[c] = u.sW2[(dq*4 + c)*65 + jj];
        #pragma unroll
        for (int a = 0; a < 4; a++){
          acc[a][0] += kv[a]*wv[0]; acc[a][1] += kv[a]*wv[1];
          acc[a][2] += kv[a]*wv[2]; acc[a][3] += kv[a]*wv[3];
        }
      }
    }
    #pragma unroll
    for (int a = 0; a < 4; a++){
      int tl = tq*4 + a;
      #pragma unroll
      for (int c = 0; c < 4; c++){
        int d = dq*4 + c;
        fpre[((size_t)(b*TT + t0 + tl))*DD + d] = acc[a][c] + f_b[d];
      }
    }
  }

  for (int i = tid; i < 32*DD; i += 256){
    int tl = i >> 7, d = i & 127;
    ypre[((size_t)(b*TT + t0 + tl))*DD + d] =
        a_W[(size_t)d*(NUM_C + DD) + sQ[tl]] * (float)sR[tl] + a_b[d];
  }
}

// ---------------------------------------------------------------------------
// Kernel A2: exact match search (unchanged, proven).
// ---------------------------------------------------------------------------
__global__ __launch_bounds__(512) void kMatch(
    const ull* __restrict__ keyLo, const ull* __restrict__ keyHi, int* __restrict__ prevA)
{
  const int b = blockIdx.x, i = threadIdx.x;
  __shared__ ull slo[TT];
  __shared__ ull shi[TT];
  slo[i] = keyLo[b*TT + i];
  shi[i] = keyHi[b*TT + i];
  __syncthreads();
  const ull mylo = slo[i], myhi = shi[i];
  int found = -1;
  for (int j = i - 1; j >= 0; j--){
    if (slo[j] == mylo && shi[j] == myhi){ found = j; break; }
  }
  prevA[b*TT + i] = found;
}

// ---------------------------------------------------------------------------
// Kernel B (R8): identical to R7 EXCEPT reductions are pure-DPP
// (red8lo_/red8all_) instead of __shfl_xor (ds_swizzle, LDS pipe).
// ---------------------------------------------------------------------------
__global__ __launch_bounds__(512, 2) void kMem(
    const float* __restrict__ wAll, const float* __restrict__ fpre, const float* __restrict__ ypre,
    const float* __restrict__ f_W, const float* __restrict__ a_W,
    const float* __restrict__ e_W, const float* __restrict__ e_b,
    const float* __restrict__ add_W, const float* __restrict__ add_b,
    const float* __restrict__ Mv0, float* __restrict__ fAll)
{
  const int b = blockIdx.x, tid = threadIdx.x;
  const int g = tid >> 3, sub = tid & 7;
  const int dd0 = 2*g;
  const int ks = sub*16;
  const int ms = sub*8;
  const int slot0 = SL(dd0);          // swizzled write slot

  float mv0[8], mv1[8];
  #pragma unroll
  for (int i = 0; i < 8; i++){
    int m = ms + i;
    mv0[i] = (m < MM) ? Mv0[(size_t)m*DD + dd0]     : 0.f;
    mv1[i] = (m < MM) ? Mv0[(size_t)m*DD + dd0 + 1] : 0.f;
  }
  float wf[2][16], wa[2][16], we[2][16], wd[2][16];
  #pragma unroll
  for (int c = 0; c < 2; c++){
    const int dd = dd0 + c;
    const float4* p;
    p = reinterpret_cast<const float4*>(&f_W[dd*256 + ks]);
    #pragma unroll
    for (int i = 0; i < 4; i++){ float4 v = p[i]; wf[c][4*i]=v.x; wf[c][4*i+1]=v.y; wf[c][4*i+2]=v.z; wf[c][4*i+3]=v.w; }
    p = reinterpret_cast<const float4*>(&a_W[(size_t)dd*(NUM_C + DD) + NUM_C + ks]);
    #pragma unroll
    for (int i = 0; i < 4; i++){ float4 v = p[i]; wa[c][4*i]=v.x; wa[c][4*i+1]=v.y; wa[c][4*i+2]=v.z; wa[c][4*i+3]=v.w; }
    p = reinterpret_cast<const float4*>(&e_W[dd*DD + ks]);
    #pragma unroll
    for (int i = 0; i < 4; i++){ float4 v = p[i]; we[c][4*i]=v.x; we[c][4*i+1]=v.y; we[c][4*i+2]=v.z; we[c][4*i+3]=v.w; }
    p = reinterpret_cast<const float4*>(&add_W[dd*DD + ks]);
    #pragma unroll
    for (int i = 0; i < 4; i++){ float4 v = p[i]; wd[c][4*i]=v.x; wd[c][4*i+1]=v.y; wd[c][4*i+2]=v.z; wd[c][4*i+3]=v.w; }
  }
  const float ebv0 = e_b[dd0],   ebv1 = e_b[dd0+1];
  const float adb0 = add_b[dd0], adb1 = add_b[dd0+1];

  __shared__ __align__(16) float bufR[160];   // swizzled (8 slices x 20)
  __shared__ __align__(16) float bufF[160];
  __shared__ __align__(16) float bufY[160];
  __shared__ __align__(16) float sW8[8*64];   // zero-padded wAll chunk
  __shared__ __align__(16) float sF8[8*128];
  __shared__ __align__(16) float sY8[8*128];
  __shared__ __align__(16) float fO8[8*128];

  const size_t base = (size_t)b*TT;

  for (int t = 0; t < TT; t++){
    const int tc = t & 7;
    if (tc == 0){
      if (t){
        if (tid < 256){
          float4 v = reinterpret_cast<const float4*>(fO8)[tid];
          reinterpret_cast<float4*>(&fAll[(base + t - 8)*DD])[tid] = v;
        }
      }
      if (tid < 256){
        float4 v = reinterpret_cast<const float4*>(&fpre[(base + t)*DD])[tid];
        reinterpret_cast<float4*>(sF8)[tid] = v;
      } else {
        float4 v = reinterpret_cast<const float4*>(&ypre[(base + t)*DD])[tid - 256];
        reinterpret_cast<float4*>(sY8)[tid - 256] = v;
      }
      {
        int rr = tid >> 6, mm = tid & 63;
        sW8[tid] = (mm < MM) ? wAll[(base + t + rr)*MM + mm] : 0.f;
      }
      __syncthreads();   // R
    }

    // wcur: 8 floats (2 b128), zeros for m >= 50
    float wcur[8];
    {
      const float4* wp = reinterpret_cast<const float4*>(&sW8[tc*64 + ms]);
      float4 w0 = wp[0], w1 = wp[1];
      wcur[0]=w0.x; wcur[1]=w0.y; wcur[2]=w0.z; wcur[3]=w0.w;
      wcur[4]=w1.x; wcur[5]=w1.y; wcur[6]=w1.z; wcur[7]=w1.w;
    }

    // ---- stage 1: read[dd] = sum_m w[m]*Mv[m][dd] ----
    {
      float r0 = 0.f, r1 = 0.f;
      #pragma unroll
      for (int i = 0; i < 8; i++){ r0 += wcur[i]*mv0[i]; r1 += wcur[i]*mv1[i]; }
      r0 = red8lo_(r0); r1 = red8lo_(r1);
      if (sub == 0) *reinterpret_cast<float2*>(&bufR[slot0]) = make_float2(r0, r1);
    }
    __syncthreads();   // A

    // ---- stage 2: f = tanh(read @ f_Wr.T + fpre) ----
    {
      const float4* x4 = reinterpret_cast<const float4*>(&bufR[sub*20]);
      float4 xa = x4[0], xb = x4[1], xc = x4[2], xd = x4[3];
      float f0 = red8lo_(dot16_(xa, xb, xc, xd, wf[0]));
      float f1 = red8lo_(dot16_(xa, xb, xc, xd, wf[1]));
      if (sub == 0){
        float2 fp = *reinterpret_cast<const float2*>(&sF8[tc*128 + dd0]);
        float fv0 = tanhf(f0 + fp.x), fv1 = tanhf(f1 + fp.y);
        *reinterpret_cast<float2*>(&bufF[slot0])        = make_float2(fv0, fv1);
        *reinterpret_cast<float2*>(&fO8[tc*128 + dd0])  = make_float2(fv0, fv1);
      }
    }
    __syncthreads();   // B

    // ---- stage 3: y = ypre + f @ a_Wf.T ----
    {
      const float4* x4 = reinterpret_cast<const float4*>(&bufF[sub*20]);
      float4 xa = x4[0], xb = x4[1], xc = x4[2], xd = x4[3];
      float y0 = red8lo_(dot16_(xa, xb, xc, xd, wa[0]));
      float y1 = red8lo_(dot16_(xa, xb, xc, xd, wa[1]));
      if (sub == 0){
        float2 yp = *reinterpret_cast<const float2*>(&sY8[tc*128 + dd0]);
        *reinterpret_cast<float2*>(&bufY[slot0]) = make_float2(y0 + yp.x, y1 + yp.y);
      }
    }
    __syncthreads();   // C

    // ---- stage 4: e,a (all lanes get totals) + Mv update (no barrier) ----
    {
      const float4* x4 = reinterpret_cast<const float4*>(&bufY[sub*20]);
      float4 xa = x4[0], xb = x4[1], xc = x4[2], xd = x4[3];
      float e0 = red8all_(dot16_(xa, xb, xc, xd, we[0]));
      float e1 = red8all_(dot16_(xa, xb, xc, xd, we[1]));
      float a0 = red8all_(dot16_(xa, xb, xc, xd, wd[0]));
      float a1 = red8all_(dot16_(xa, xb, xc, xd, wd[1]));
      float ed0 = sigmoidf_(e0 + ebv0), ed1 = sigmoidf_(e1 + ebv1);
      float ad0 = tanhf(a0 + adb0),     ad1 = tanhf(a1 + adb1);
      #pragma unroll
      for (int i = 0; i < 8; i++){
        float wv = wcur[i];
        mv0[i] = mv0[i]*(1.f - wv*ed0) + wv*ad0;
        mv1[i] = mv1[i]*(1.f - wv*ed1) + wv*ad1;
      }
    }
  }

  __syncthreads();
  if (tid < 256){
    float4 v = reinterpret_cast<const float4*>(fO8)[tid];
    reinterpret_cast<float4*>(&fAll[(base + TT - 8)*DD])[tid] = v;
  }
}

// ---------------------------------------------------------------------------
// Kernel D: gpre GEMM, cell-major output (unchanged, proven).
// ---------------------------------------------------------------------------
__global__ __launch_bounds__(256) void kGate(
    const float* __restrict__ fAll, const float* __restrict__ Wih,
    const float* __restrict__ bih, const float* __restrict__ bhh,
    float* __restrict__ gpre)
{
  const int jt = blockIdx.x;
  const int rt = blockIdx.y;
  const int tid = threadIdx.x;
  __shared__ float sW[64*129];
  __shared__ float sF[32*129];
  for (int i = tid; i < 64*128; i += 256){
    int jj = i >> 7, k = i & 127;
    sW[jj*129 + k] = Wih[(size_t)(jt*64 + jj)*128 + k];
  }
  for (int i = tid; i < 32*128; i += 256){
    int rr = i >> 7, k = i & 127;
    sF[rr*129 + k] = fAll[(size_t)(rt*32 + rr)*128 + k];
  }
  __syncthreads();
  const int jq = tid & 31, rq = tid >> 5;
  float acc[4][2];
  #pragma unroll
  for (int a = 0; a < 4; a++){ acc[a][0] = 0.f; acc[a][1] = 0.f; }
  for (int k = 0; k < 128; k++){
    float fv[4], wv[2];
    #pragma unroll
    for (int a = 0; a < 4; a++) fv[a] = sF[(rq*4 + a)*129 + k];
    wv[0] = sW[(jq*2 + 0)*129 + k];
    wv[1] = sW[(jq*2 + 1)*129 + k];
    #pragma unroll
    for (int a = 0; a < 4; a++){ acc[a][0] += fv[a]*wv[0]; acc[a][1] += fv[a]*wv[1]; }
  }
  #pragma unroll
  for (int a = 0; a < 4; a++){
    int rowi = rt*32 + rq*4 + a;
    #pragma unroll
    for (int c = 0; c < 2; c++){
      int j = jt*64 + jq*2 + c;           // gate-major: gate = j>>7, cell = j&127
      int cell = j & 127, gt = j >> 7;
      gpre[(size_t)rowi*512 + cell*4 + gt] = acc[a][c] + bih[j] + bhh[j];
    }
  }
}

// ---------------------------------------------------------------------------
// Kernel C: LSTM (unchanged from R6/R7, proven).
// ---------------------------------------------------------------------------
__global__ __launch_bounds__(512, 2) void kLstm(
    const float* __restrict__ gpre, const int* __restrict__ prevA,
    const float* __restrict__ Whh,
    float* __restrict__ Hh, float* __restrict__ Ch)
{
  const int b = blockIdx.x, tid = threadIdx.x;
  const int jo = tid >> 2, kc = tid & 3;
  const int wslot = (jo >> 5)*36 + (jo & 31);

  float whh[4][32];
  #pragma unroll
  for (int g = 0; g < 4; g++){
    const float4* W4 = reinterpret_cast<const float4*>(&Whh[(size_t)(g*128 + jo)*128 + kc*32]);
    #pragma unroll
    for (int i = 0; i < 8; i++){
      float4 v = W4[i];
      whh[g][4*i] = v.x; whh[g][4*i+1] = v.y; whh[g][4*i+2] = v.z; whh[g][4*i+3] = v.w;
    }
  }

  __shared__ __align__(16) float xh[2][144];
  __shared__ __align__(16) float gbuf[2][8*512];
  __shared__ int spv[TT];

  const size_t base = (size_t)b*TT;
  float4 gr0, gr1;
  {
    const float4* g0 = reinterpret_cast<const float4*>(&gpre[base*512]);
    float4 a = g0[tid*2], c = g0[tid*2+1];
    float4* gb4 = reinterpret_cast<float4*>(gbuf[0]);
    gb4[tid*2] = a; gb4[tid*2+1] = c;
    const float4* g1 = reinterpret_cast<const float4*>(&gpre[(base + 8)*512]);
    gr0 = g1[tid*2]; gr1 = g1[tid*2+1];
    spv[tid] = prevA[base + tid];
    if (tid < DD) xh[0][(tid >> 5)*36 + (tid & 31)] = 0.f;
  }
  __syncthreads();

  float cin_cur = 0.f;

  for (int t = 0; t < TT; t++){
    const int tc = t & 7, p = t & 1, pc = (t >> 3) & 1;
    if (tc == 0 && t){
      __syncthreads();
      {
        float4* gb4 = reinterpret_cast<float4*>(gbuf[pc]);
        gb4[tid*2] = gr0; gb4[tid*2+1] = gr1;
      }
      if (t + 8 < TT){
        const float4* gp4 = reinterpret_cast<const float4*>(&gpre[(base + t + 8)*512]);
        gr0 = gp4[tid*2]; gr1 = gp4[tid*2+1];
      }
      __syncthreads();
    } else if (t) {
      __syncthreads();
    }

    const size_t row = base + t;

    int pv2 = -1; float preH = 0.f, preC = 0.f;
    if (t + 1 < TT){
      pv2 = spv[t + 1];
      if (pv2 >= 0 && pv2 < t){
        preH = Hh[(base + pv2)*DD + jo];
        preC = Ch[(base + pv2)*DD + jo];
      }
    }

    const float4 gp = *reinterpret_cast<const float4*>(&gbuf[pc][tc*512 + 4*jo]);

    float a0=0.f,a1=0.f,a2=0.f,a3=0.f;
    {
      const float4* x4 = reinterpret_cast<const float4*>(&xh[p][kc*36]);
      #pragma unroll
      for (int i = 0; i < 8; i++){
        float4 xv = x4[i];
        a0 += xv.x*whh[0][4*i]; a0 += xv.y*whh[0][4*i+1]; a0 += xv.z*whh[0][4*i+2]; a0 += xv.w*whh[0][4*i+3];
        a1 += xv.x*whh[1][4*i]; a1 += xv.y*whh[1][4*i+1]; a1 += xv.z*whh[1][4*i+2]; a1 += xv.w*whh[1][4*i+3];
        a2 += xv.x*whh[2][4*i]; a2 += xv.y*whh[2][4*i+1]; a2 += xv.z*whh[2][4*i+2]; a2 += xv.w*whh[2][4*i+3];
        a3 += xv.x*whh[3][4*i]; a3 += xv.y*whh[3][4*i+1]; a3 += xv.z*whh[3][4*i+2]; a3 += xv.w*whh[3][4*i+3];
      }
    }
    a0 = quadSum_(a0); a1 = quadSum_(a1); a2 = quadSum_(a2); a3 = quadSum_(a3);

    const float ig = gp.x + a0, fg = gp.y + a1, gg = gp.z + a2, og = gp.w + a3;
    const float cn = sigmoidf_(fg)*cin_cur + sigmoidf_(ig)*tanhf(gg);
    const float hn = sigmoidf_(og)*tanhf(cn);

    if (kc == 0){
      Hh[row*DD + jo] = hn;
      Ch[row*DD + jo] = cn;
    }

    float hin_n, cin_n;
    if (pv2 < 0 || pv2 >= t){ hin_n = hn; cin_n = cn; }
    else                     { hin_n = preH; cin_n = preC; }
    if (kc == 0) xh[1 - p][wslot] = hin_n;
    cin_cur = cin_n;
  }
}

// ---------------------------------------------------------------------------
// Kernel E: output head (unchanged, proven).
// ---------------------------------------------------------------------------
__global__ __launch_bounds__(256) void kOut(
    const float* __restrict__ Hh, const float* __restrict__ p_W,
    const float* __restrict__ p_b, float* __restrict__ out)
{
  const int row = blockIdx.x*16 + (threadIdx.x >> 4);
  const int l = threadIdx.x & 15;
  const float4* h4 = reinterpret_cast<const float4*>(&Hh[(size_t)row*DD + l*8]);
  const float4* w4 = reinterpret_cast<const float4*>(&p_W[l*8]);
  float4 ha = h4[0], hb = h4[1], wa = w4[0], wb = w4[1];
  float s = ha.x*wa.x + ha.y*wa.y + ha.z*wa.z + ha.w*wa.w
          + hb.x*wb.x + hb.y*wb.y + hb.z*wb.z + hb.w*wb.w;
  s += __shfl_xor(s, 1); s += __shfl_xor(s, 2);
  s += __shfl_xor(s, 4); s += __shfl_xor(s, 8);
  if (l == 0) out[row] = sigmoidf_(s + p_b[0]);
}

// ---------------------------------------------------------------------------
// Launch.
// ---------------------------------------------------------------------------
extern "C" void kernel_launch(void* const* d_in, const int* in_sizes, int n_in,
                              void* d_out, int out_size, void* d_ws, size_t ws_size,
                              hipStream_t stream) {
  const int*   q     = (const int*)  d_in[0];
  const int*   r     = (const int*)  d_in[1];
  const float* k_emb = (const float*)d_in[2];
  const float* Mk    = (const float*)d_in[3];
  const float* Mv0   = (const float*)d_in[4];
  const float* f_W   = (const float*)d_in[5];
  const float* f_b   = (const float*)d_in[6];
  const float* a_W   = (const float*)d_in[7];
  const float* a_b   = (const float*)d_in[8];
  const float* e_W   = (const float*)d_in[9];
  const float* e_b   = (const float*)d_in[10];
  const float* add_W = (const float*)d_in[11];
  const float* add_b = (const float*)d_in[12];
  const float* Wih   = (const float*)d_in[13];
  const float* Whh   = (const float*)d_in[14];
  const float* bih   = (const float*)d_in[15];
  const float* bhh   = (const float*)d_in[16];
  const float* p_W   = (const float*)d_in[17];
  const float* p_b   = (const float*)d_in[18];
  float* out = (float*)d_out;

  char* ws = (char*)d_ws;
  size_t off = 0;
  auto alloc = [&](size_t bytes) -> char* {
    char* p = ws + off;
    off += (bytes + 255) & ~(size_t)255;
    return p;
  };
  float* wAll  = (float*)alloc((size_t)BB*TT*MM*4);
  float* fpre  = (float*)alloc((size_t)BB*TT*DD*4);
  float* ypre  = (float*)alloc((size_t)BB*TT*DD*4);
  float* fAll  = (float*)alloc((size_t)BB*TT*DD*4);
  float* gpre  = (float*)alloc((size_t)BB*TT*512*4);
  float* Hh    = (float*)alloc((size_t)BB*TT*DD*4);
  float* Ch    = (float*)alloc((size_t)BB*TT*DD*4);
  ull*   keyLo = (ull*)  alloc((size_t)BB*TT*8);
  ull*   keyHi = (ull*)  alloc((size_t)BB*TT*8);
  int*   prevA = (int*)  alloc((size_t)BB*TT*4);
  (void)ws_size; (void)in_sizes; (void)n_in; (void)out_size;

  kPre  <<<dim3(16, 32), 256, 0, stream>>>(q, r, k_emb, Mk, f_W, f_b, a_W, a_b,
                                           wAll, keyLo, keyHi, fpre, ypre);
  kMatch<<<32, 512, 0, stream>>>(keyLo, keyHi, prevA);
  kMem  <<<32, 512, 0, stream>>>(wAll, fpre, ypre, f_W, a_W, e_W, e_b, add_W, add_b,
                                 Mv0, fAll);
  kGate <<<dim3(8, 512), 256, 0, stream>>>(fAll, Wih, bih, bhh, gpre);
  kLstm <<<32, 512, 0, stream>>>(gpre, prevA, Whh, Hh, Ch);
  kOut  <<<(BB*TT)/16, 256, 0, stream>>>(Hh, p_W, p_b, out);
}